// Round 1
// baseline (550.348 us; speedup 1.0000x reference)
//
#include <hip/hip_runtime.h>
#include <math.h>

#define B 8
#define S 1024
#define D 1024
#define F 3584

// ---------------- block-wide sum for 256-thread blocks ----------------
__device__ __forceinline__ float block_sum256(float v, volatile float* buf) {
  #pragma unroll
  for (int o = 32; o; o >>= 1) v += __shfl_down(v, o);   // wave64 reduce
  __syncthreads();                                        // protect buf reuse
  if ((threadIdx.x & 63) == 0) buf[threadIdx.x >> 6] = v;
  __syncthreads();
  return buf[0] + buf[1] + buf[2] + buf[3];
}

// K1: h1[b] = rmsnorm(hidden[b,0,:], ln1_w).  grid=B, block=256.
__global__ void k_rms1(const float* __restrict__ hs, const float* __restrict__ w,
                       float* __restrict__ h1) {
  __shared__ float buf[4];
  int b = blockIdx.x;
  const float* x = hs + (size_t)b * S * D;
  float xv[4]; float ss = 0.f;
  #pragma unroll
  for (int t = 0; t < 4; t++) {
    int idx = threadIdx.x + 256 * t;
    xv[t] = x[idx];
    ss += xv[t] * xv[t];
  }
  float tot = block_sum256(ss, buf);
  float scale = rsqrtf(tot * (1.f / (float)D) + 1e-6f);
  #pragma unroll
  for (int t = 0; t < 4; t++) {
    int idx = threadIdx.x + 256 * t;
    h1[b * D + idx] = xv[t] * scale * w[idx];
  }
}

// K2/K3: Y[8,1024] += X[8,1024] @ W[1024,1024], split-K via atomics.
// grid=(16, KS), block=64. Each thread: one output col, all 8 batches.
__global__ void k_mv1024(const float* __restrict__ X, const float* __restrict__ W,
                         float* __restrict__ Y, int kchunk) {
  int j = blockIdx.x * 64 + threadIdx.x;
  int i0 = blockIdx.y * kchunk;
  const float* Wp = W + (size_t)i0 * D + j;
  float acc[8] = {0, 0, 0, 0, 0, 0, 0, 0};
  #pragma unroll 4
  for (int i = i0; i < i0 + kchunk; i++) {
    float w = *Wp; Wp += D;
    #pragma unroll
    for (int bb = 0; bb < 8; bb++) acc[bb] += X[bb * D + i] * w;  // X load is wave-uniform -> s_load
  }
  #pragma unroll
  for (int bb = 0; bb < 8; bb++) atomicAdd(&Y[bb * D + j], acc[bb]);
}

// K4: xr = hidden[b,0]+attn_out; h2 = rmsnorm(xr, ln2); router top-1. grid=B, block=256.
__global__ void k_mid(const float* __restrict__ hs, const float* __restrict__ x1acc,
                      const float* __restrict__ ln2, const float* __restrict__ rw,
                      float* __restrict__ xr, float* __restrict__ h2,
                      float* __restrict__ topw, int* __restrict__ sel) {
  __shared__ float buf[4];
  int b = blockIdx.x;
  const float* x0 = hs + (size_t)b * S * D;
  float xv[4]; float ss = 0.f;
  #pragma unroll
  for (int t = 0; t < 4; t++) {
    int idx = threadIdx.x + 256 * t;
    xv[t] = x0[idx] + x1acc[b * D + idx];
    xr[b * D + idx] = xv[t];
    ss += xv[t] * xv[t];
  }
  float tot = block_sum256(ss, buf);
  float scale = rsqrtf(tot * (1.f / (float)D) + 1e-6f);
  float r0 = 0.f, r1 = 0.f;
  #pragma unroll
  for (int t = 0; t < 4; t++) {
    int idx = threadIdx.x + 256 * t;
    float hv = xv[t] * scale * ln2[idx];
    h2[b * D + idx] = hv;
    r0 += hv * rw[idx * 2 + 0];
    r1 += hv * rw[idx * 2 + 1];
  }
  r0 = block_sum256(r0, buf);
  r1 = block_sum256(r1, buf);
  if (threadIdx.x == 0) {
    float m = fmaxf(r0, r1);
    float e0 = __expf(r0 - m), e1 = __expf(r1 - m);
    float inv = 1.f / (e0 + e1);
    float p0 = e0 * inv, p1 = e1 * inv;
    topw[b] = fmaxf(p0, p1);
    sel[b] = (p1 > p0) ? 1 : 0;   // argmax, first index wins ties
  }
}

// K5: g[e][b][:] = silu(h2[b] @ gate_w[e]) * (h2[b] @ up_w[e]) for BOTH experts.
// grid=(F/64, 2), block=64.
__global__ void k_gateup(const float* __restrict__ h2, const float* __restrict__ gw,
                         const float* __restrict__ uw, float* __restrict__ g) {
  int e = blockIdx.y;
  int j = blockIdx.x * 64 + threadIdx.x;
  const float* G = gw + (size_t)e * D * F + j;
  const float* U = uw + (size_t)e * D * F + j;
  float ag[8] = {0, 0, 0, 0, 0, 0, 0, 0};
  float au[8] = {0, 0, 0, 0, 0, 0, 0, 0};
  #pragma unroll 2
  for (int i = 0; i < D; i++) {
    float gv = G[(size_t)i * F];
    float uv = U[(size_t)i * F];
    #pragma unroll
    for (int bb = 0; bb < 8; bb++) {
      float xv = h2[bb * D + i];
      ag[bb] += xv * gv;
      au[bb] += xv * uv;
    }
  }
  #pragma unroll
  for (int bb = 0; bb < 8; bb++) {
    float a = ag[bb];
    float sv = a / (1.f + __expf(-a));   // silu
    g[((size_t)e * 8 + bb) * F + j] = sv * au[bb];
  }
}

// K6: y[e][b][:] += g[e][b][:] @ down_w[e], split-K via atomics.
// grid=(16, 4, 2), block=64.
__global__ void k_down(const float* __restrict__ g, const float* __restrict__ dw,
                       float* __restrict__ y, int kchunk) {
  int e = blockIdx.z;
  int j = blockIdx.x * 64 + threadIdx.x;
  int i0 = blockIdx.y * kchunk;
  const float* W = dw + (size_t)e * F * D + (size_t)i0 * D + j;
  const float* X = g + (size_t)e * 8 * F;
  float acc[8] = {0, 0, 0, 0, 0, 0, 0, 0};
  #pragma unroll 4
  for (int i = i0; i < i0 + kchunk; i++) {
    float w = *W; W += D;
    #pragma unroll
    for (int bb = 0; bb < 8; bb++) acc[bb] += X[bb * F + i] * w;
  }
  #pragma unroll
  for (int bb = 0; bb < 8; bb++) atomicAdd(&y[((size_t)e * 8 + bb) * D + j], acc[bb]);
}

// K7: x2 = xr + top_w*y[sel]; final rmsnorm; logits = x2n @ score_w. grid=B, block=256.
__global__ void k_final(const float* __restrict__ xr, const float* __restrict__ y,
                        const float* __restrict__ topw, const int* __restrict__ sel,
                        const float* __restrict__ flw, const float* __restrict__ sw,
                        float* __restrict__ out) {
  __shared__ float buf[4];
  int b = blockIdx.x;
  int e = sel[b];
  float tw = topw[b];
  float xv[4]; float ss = 0.f;
  #pragma unroll
  for (int t = 0; t < 4; t++) {
    int idx = threadIdx.x + 256 * t;
    xv[t] = xr[b * D + idx] + tw * y[((size_t)e * 8 + b) * D + idx];
    ss += xv[t] * xv[t];
  }
  float tot = block_sum256(ss, buf);
  float scale = rsqrtf(tot * (1.f / (float)D) + 1e-6f);
  float l0 = 0.f, l1 = 0.f;
  #pragma unroll
  for (int t = 0; t < 4; t++) {
    int idx = threadIdx.x + 256 * t;
    float xn = xv[t] * scale * flw[idx];
    l0 += xn * sw[idx * 2 + 0];
    l1 += xn * sw[idx * 2 + 1];
  }
  l0 = block_sum256(l0, buf);
  l1 = block_sum256(l1, buf);
  if (threadIdx.x == 0) { out[b * 2 + 0] = l0; out[b * 2 + 1] = l1; }
}

extern "C" void kernel_launch(void* const* d_in, const int* in_sizes, int n_in,
                              void* d_out, int out_size, void* d_ws, size_t ws_size,
                              hipStream_t stream) {
  const float* hs  = (const float*)d_in[0];
  const float* ln1 = (const float*)d_in[1];
  // d_in[2]=q_w, d_in[3]=k_w: dead — token-0 causal attention only needs V.
  const float* vw  = (const float*)d_in[4];
  const float* ow  = (const float*)d_in[5];
  const float* ln2 = (const float*)d_in[6];
  const float* rw  = (const float*)d_in[7];
  const float* gw  = (const float*)d_in[8];
  const float* uw  = (const float*)d_in[9];
  const float* dw  = (const float*)d_in[10];
  const float* flw = (const float*)d_in[11];
  const float* sw  = (const float*)d_in[12];

  float* ws    = (float*)d_ws;
  float* h1    = ws;               // 8192
  float* v0    = ws + 8192;        // 8192  (atomic target)
  float* x1acc = ws + 16384;       // 8192  (atomic target)
  float* y     = ws + 24576;       // 16384 (atomic target)
  float* xr    = ws + 40960;       // 8192
  float* h2    = ws + 49152;       // 8192
  float* g     = ws + 57344;       // 2*8*3584 = 57344
  float* topw  = ws + 114688;      // 8
  int*   sel   = (int*)(ws + 114696); // 8

  // zero the atomic-accumulated regions (ws is poisoned 0xAA before each call)
  hipMemsetAsync(v0, 0, (size_t)(8192 + 8192 + 16384) * sizeof(float), stream);

  k_rms1<<<8, 256, 0, stream>>>(hs, ln1, h1);
  k_mv1024<<<dim3(16, 8), 64, 0, stream>>>(h1, vw, v0, 128);     // v0 = h1 @ v_w
  k_mv1024<<<dim3(16, 8), 64, 0, stream>>>(v0, ow, x1acc, 128);  // attn_out = v0 @ o_w
  k_mid<<<8, 256, 0, stream>>>(hs, x1acc, ln2, rw, xr, h2, topw, sel);
  k_gateup<<<dim3(F / 64, 2), 64, 0, stream>>>(h2, gw, uw, g);
  k_down<<<dim3(16, 4, 2), 64, 0, stream>>>(g, dw, y, F / 4);
  k_final<<<8, 256, 0, stream>>>(xr, y, topw, sel, flw, sw, (float*)d_out);
}

// Round 2
// 222.941 us; speedup vs baseline: 2.4686x; 2.4686x over previous
//
#include <hip/hip_runtime.h>
#include <math.h>

#define B 8
#define S 1024
#define D 1024
#define F 3584

// ---------------- block-wide sum for 256-thread blocks ----------------
__device__ __forceinline__ float block_sum256(float v, volatile float* buf) {
  #pragma unroll
  for (int o = 32; o; o >>= 1) v += __shfl_down(v, o);   // wave64 reduce
  __syncthreads();
  if ((threadIdx.x & 63) == 0) buf[threadIdx.x >> 6] = v;
  __syncthreads();
  return buf[0] + buf[1] + buf[2] + buf[3];
}

// K1: h1[b] = rmsnorm(hidden[b,0,:], ln1_w).  grid=B, block=256.
__global__ void k_rms1(const float* __restrict__ hs, const float* __restrict__ w,
                       float* __restrict__ h1) {
  __shared__ float buf[4];
  int b = blockIdx.x;
  const float* x = hs + (size_t)b * S * D;
  float xv[4]; float ss = 0.f;
  #pragma unroll
  for (int t = 0; t < 4; t++) {
    int idx = threadIdx.x + 256 * t;
    xv[t] = x[idx];
    ss += xv[t] * xv[t];
  }
  float tot = block_sum256(ss, buf);
  float scale = rsqrtf(tot * (1.f / (float)D) + 1e-6f);
  #pragma unroll
  for (int t = 0; t < 4; t++) {
    int idx = threadIdx.x + 256 * t;
    h1[b * D + idx] = xv[t] * scale * w[idx];
  }
}

// Y[8,1024] += X[8,1024] @ W[1024,1024], split-K atomics, float2 weights.
// grid=(D/128, KS), block=64. Thread: 2 output cols, all 8 batches.
__global__ void k_mv1024(const float* __restrict__ X, const float* __restrict__ W,
                         float* __restrict__ Y, int kchunk) {
  int j = (blockIdx.x * 64 + threadIdx.x) * 2;
  int i0 = blockIdx.y * kchunk;
  const float2* Wp = (const float2*)(W + (size_t)i0 * D + j);
  float a0[8] = {0,0,0,0,0,0,0,0}, a1[8] = {0,0,0,0,0,0,0,0};
  #pragma unroll 4
  for (int i = i0; i < i0 + kchunk; i++) {
    float2 w = *Wp; Wp += D / 2;
    #pragma unroll
    for (int bb = 0; bb < 8; bb++) {
      float xv = X[bb * D + i];   // wave-uniform -> scalar load
      a0[bb] += xv * w.x;
      a1[bb] += xv * w.y;
    }
  }
  #pragma unroll
  for (int bb = 0; bb < 8; bb++) {
    atomicAdd(&Y[bb * D + j],     a0[bb]);
    atomicAdd(&Y[bb * D + j + 1], a1[bb]);
  }
}

// K4: xr = hidden[b,0]+attn_out; h2 = rmsnorm(xr, ln2); router top-1. grid=B, block=256.
__global__ void k_mid(const float* __restrict__ hs, const float* __restrict__ x1acc,
                      const float* __restrict__ ln2, const float* __restrict__ rw,
                      float* __restrict__ xr, float* __restrict__ h2,
                      float* __restrict__ topw, int* __restrict__ sel) {
  __shared__ float buf[4];
  int b = blockIdx.x;
  const float* x0 = hs + (size_t)b * S * D;
  float xv[4]; float ss = 0.f;
  #pragma unroll
  for (int t = 0; t < 4; t++) {
    int idx = threadIdx.x + 256 * t;
    xv[t] = x0[idx] + x1acc[b * D + idx];
    xr[b * D + idx] = xv[t];
    ss += xv[t] * xv[t];
  }
  float tot = block_sum256(ss, buf);
  float scale = rsqrtf(tot * (1.f / (float)D) + 1e-6f);
  float r0 = 0.f, r1 = 0.f;
  #pragma unroll
  for (int t = 0; t < 4; t++) {
    int idx = threadIdx.x + 256 * t;
    float hv = xv[t] * scale * ln2[idx];
    h2[b * D + idx] = hv;
    r0 += hv * rw[idx * 2 + 0];
    r1 += hv * rw[idx * 2 + 1];
  }
  r0 = block_sum256(r0, buf);
  r1 = block_sum256(r1, buf);
  if (threadIdx.x == 0) {
    float m = fmaxf(r0, r1);
    float e0 = __expf(r0 - m), e1 = __expf(r1 - m);
    float inv = 1.f / (e0 + e1);
    float p0 = e0 * inv, p1 = e1 * inv;
    topw[b] = fmaxf(p0, p1);
    sel[b] = (p1 > p0) ? 1 : 0;
  }
}

// K5: split-K partial sums of h2@gate_w[e] and h2@up_w[e] (both experts).
// grid=(F/128, KS, 2), block=64, float2 weight loads. Atomic into ag/au.
__global__ void k_gateup(const float* __restrict__ h2, const float* __restrict__ gw,
                         const float* __restrict__ uw, float* __restrict__ agb,
                         float* __restrict__ aub, int kchunk) {
  int e = blockIdx.z;
  int j = (blockIdx.x * 64 + threadIdx.x) * 2;
  int i0 = blockIdx.y * kchunk;
  const float2* G = (const float2*)(gw + (size_t)e * D * F + (size_t)i0 * F + j);
  const float2* U = (const float2*)(uw + (size_t)e * D * F + (size_t)i0 * F + j);
  float g0[8] = {0,0,0,0,0,0,0,0}, g1[8] = {0,0,0,0,0,0,0,0};
  float u0[8] = {0,0,0,0,0,0,0,0}, u1[8] = {0,0,0,0,0,0,0,0};
  #pragma unroll 2
  for (int i = i0; i < i0 + kchunk; i++) {
    float2 gv = *G; G += F / 2;
    float2 uv = *U; U += F / 2;
    #pragma unroll
    for (int bb = 0; bb < 8; bb++) {
      float xv = h2[bb * D + i];   // wave-uniform
      g0[bb] += xv * gv.x;
      g1[bb] += xv * gv.y;
      u0[bb] += xv * uv.x;
      u1[bb] += xv * uv.y;
    }
  }
  #pragma unroll
  for (int bb = 0; bb < 8; bb++) {
    size_t o = ((size_t)e * 8 + bb) * F + j;
    atomicAdd(&agb[o],     g0[bb]);
    atomicAdd(&agb[o + 1], g1[bb]);
    atomicAdd(&aub[o],     u0[bb]);
    atomicAdd(&aub[o + 1], u1[bb]);
  }
}

// K6: g = silu(ag) * au elementwise over 2*8*F. grid=(2*8*F/256), block=256.
__global__ void k_silu(const float* __restrict__ agb, const float* __restrict__ aub,
                       float* __restrict__ g) {
  int idx = blockIdx.x * 256 + threadIdx.x;
  float a = agb[idx];
  g[idx] = (a / (1.f + __expf(-a))) * aub[idx];
}

// K7: y[e][b][:] += g[e][b][:] @ down_w[e], split-K atomics, float2.
// grid=(D/128, KS, 2), block=64.
__global__ void k_down(const float* __restrict__ g, const float* __restrict__ dw,
                       float* __restrict__ y, int kchunk) {
  int e = blockIdx.z;
  int j = (blockIdx.x * 64 + threadIdx.x) * 2;
  int i0 = blockIdx.y * kchunk;
  const float2* W = (const float2*)(dw + (size_t)e * F * D + (size_t)i0 * D + j);
  const float* X = g + (size_t)e * 8 * F;
  float a0[8] = {0,0,0,0,0,0,0,0}, a1[8] = {0,0,0,0,0,0,0,0};
  #pragma unroll 4
  for (int i = i0; i < i0 + kchunk; i++) {
    float2 w = *W; W += D / 2;
    #pragma unroll
    for (int bb = 0; bb < 8; bb++) {
      float xv = X[bb * F + i];   // wave-uniform
      a0[bb] += xv * w.x;
      a1[bb] += xv * w.y;
    }
  }
  #pragma unroll
  for (int bb = 0; bb < 8; bb++) {
    atomicAdd(&y[((size_t)e * 8 + bb) * D + j],     a0[bb]);
    atomicAdd(&y[((size_t)e * 8 + bb) * D + j + 1], a1[bb]);
  }
}

// K8: x2 = xr + top_w*y[sel]; final rmsnorm; logits. grid=B, block=256.
__global__ void k_final(const float* __restrict__ xr, const float* __restrict__ y,
                        const float* __restrict__ topw, const int* __restrict__ sel,
                        const float* __restrict__ flw, const float* __restrict__ sw,
                        float* __restrict__ out) {
  __shared__ float buf[4];
  int b = blockIdx.x;
  int e = sel[b];
  float tw = topw[b];
  float xv[4]; float ss = 0.f;
  #pragma unroll
  for (int t = 0; t < 4; t++) {
    int idx = threadIdx.x + 256 * t;
    xv[t] = xr[b * D + idx] + tw * y[((size_t)e * 8 + b) * D + idx];
    ss += xv[t] * xv[t];
  }
  float tot = block_sum256(ss, buf);
  float scale = rsqrtf(tot * (1.f / (float)D) + 1e-6f);
  float l0 = 0.f, l1 = 0.f;
  #pragma unroll
  for (int t = 0; t < 4; t++) {
    int idx = threadIdx.x + 256 * t;
    float xn = xv[t] * scale * flw[idx];
    l0 += xn * sw[idx * 2 + 0];
    l1 += xn * sw[idx * 2 + 1];
  }
  l0 = block_sum256(l0, buf);
  l1 = block_sum256(l1, buf);
  if (threadIdx.x == 0) { out[b * 2 + 0] = l0; out[b * 2 + 1] = l1; }
}

extern "C" void kernel_launch(void* const* d_in, const int* in_sizes, int n_in,
                              void* d_out, int out_size, void* d_ws, size_t ws_size,
                              hipStream_t stream) {
  const float* hs  = (const float*)d_in[0];
  const float* ln1 = (const float*)d_in[1];
  // d_in[2]=q_w, d_in[3]=k_w: dead — token-0 causal attention only needs V.
  const float* vw  = (const float*)d_in[4];
  const float* ow  = (const float*)d_in[5];
  const float* ln2 = (const float*)d_in[6];
  const float* rw  = (const float*)d_in[7];
  const float* gw  = (const float*)d_in[8];
  const float* uw  = (const float*)d_in[9];
  const float* dw  = (const float*)d_in[10];
  const float* flw = (const float*)d_in[11];
  const float* sw  = (const float*)d_in[12];

  float* ws = (float*)d_ws;
  // --- atomic-accumulated (contiguous, single memset) ---
  float* v0    = ws;                // 8192
  float* x1acc = ws + 8192;         // 8192
  float* y     = ws + 16384;        // 16384
  float* agb   = ws + 32768;        // 57344
  float* aub   = ws + 90112;        // 57344
  // --- plain scratch ---
  float* h1    = ws + 147456;       // 8192
  float* xr    = ws + 155648;       // 8192
  float* h2    = ws + 163840;       // 8192
  float* g     = ws + 172032;       // 57344
  float* topw  = ws + 229376;       // 8
  int*   sel   = (int*)(ws + 229384); // 8

  hipMemsetAsync(v0, 0, (size_t)147456 * sizeof(float), stream);

  k_rms1<<<8, 256, 0, stream>>>(hs, ln1, h1);
  k_mv1024<<<dim3(8, 32), 64, 0, stream>>>(h1, vw, v0, 32);      // v0 = h1 @ v_w
  k_mv1024<<<dim3(8, 32), 64, 0, stream>>>(v0, ow, x1acc, 32);   // attn_out
  k_mid<<<8, 256, 0, stream>>>(hs, x1acc, ln2, rw, xr, h2, topw, sel);
  k_gateup<<<dim3(F / 128, 16, 2), 64, 0, stream>>>(h2, gw, uw, agb, aub, D / 16);
  k_silu<<<(2 * 8 * F) / 256, 256, 0, stream>>>(agb, aub, g);
  k_down<<<dim3(D / 128, 28, 2), 64, 0, stream>>>(g, dw, y, F / 28);
  k_final<<<8, 256, 0, stream>>>(xr, y, topw, sel, flw, sw, (float*)d_out);
}